// Round 4
// baseline (227.441 us; speedup 1.0000x reference)
//
#include <hip/hip_runtime.h>
#include <hip/hip_bf16.h>
#include <stdint.h>

#define D_MODEL 1024
#define NH 16
#define HD 64
#define SEQ 2048
#define BATCH 2
#define ROWS (BATCH * SEQ)   // 4096
#define KDIM 1024
#define NQKV 3072

typedef unsigned short u16;
typedef short bf16x8 __attribute__((ext_vector_type(8)));   // 8 bf16 in 4 VGPRs
typedef short bf16x4 __attribute__((ext_vector_type(4)));   // 4 bf16 in 2 VGPRs
typedef float f32x4 __attribute__((ext_vector_type(4)));

__device__ __forceinline__ u16 f2bf(float f) {
  union { float f; unsigned u; } x; x.f = f;
  unsigned r = x.u + 0x7fff + ((x.u >> 16) & 1);   // RNE
  return (u16)(r >> 16);
}

// packed RNE f32x2 -> bf16x2 (v_cvt_pk_bf16_f32 on gfx950)
__device__ __forceinline__ bf16x4 pack4(float a, float b, float c, float d) {
  union { __hip_bfloat162 h2[2]; bf16x4 v; } u;
  u.h2[0] = __float22bfloat162_rn(make_float2(a, b));
  u.h2[1] = __float22bfloat162_rn(make_float2(c, d));
  return u.v;
}
__device__ __forceinline__ ushort4 packu4(float a, float b, float c, float d) {
  union { __hip_bfloat162 h2[2]; ushort4 v; } u;
  u.h2[0] = __float22bfloat162_rn(make_float2(a, b));
  u.h2[1] = __float22bfloat162_rn(make_float2(c, d));
  return u.v;
}

#ifndef HAVE_MFMA16_1K
#if defined(__has_builtin)
#if __has_builtin(__builtin_amdgcn_mfma_f32_16x16x16bf16_1k)
#define HAVE_MFMA16_1K 1
#endif
#endif
#endif
__device__ __forceinline__ f32x4 mfma16(bf16x4 a, bf16x4 b, f32x4 c) {
#ifdef HAVE_MFMA16_1K
  return __builtin_amdgcn_mfma_f32_16x16x16bf16_1k(a, b, c, 0, 0, 0);
#else
  bf16x8 a8 = {a[0], a[1], a[2], a[3], 0, 0, 0, 0};
  bf16x8 b8 = {b[0], b[1], b[2], b[3], 0, 0, 0, 0};
  return __builtin_amdgcn_mfma_f32_16x16x32_bf16(a8, b8, c, 0, 0, 0);
#endif
}

// async global->LDS, 16B/lane. LDS dst is wave-uniform base + lane*16;
// global SOURCE address is per-lane arbitrary (16B contiguous) -> swizzle there.
__device__ __forceinline__ void gload16(const u16* g, u16* l) {
  __builtin_amdgcn_global_load_lds(
      (const __attribute__((address_space(1))) unsigned int*)g,
      (__attribute__((address_space(3))) unsigned int*)l, 16, 0, 0);
}

// ---- fused prep: query cvt, weight transposes, rope table, bias-init of out ----
__global__ void prep_kernel(const float* __restrict__ query, u16* __restrict__ q_bf,
                            const float* __restrict__ W_qkv, u16* __restrict__ wt_qkv,
                            const float* __restrict__ W_out, u16* __restrict__ wt_out,
                            float2* __restrict__ rope_tab,
                            const float* __restrict__ b_out, float* __restrict__ out) {
  __shared__ float tile[32][33];
  const int blk = blockIdx.x, tid = threadIdx.x;
  if (blk < 4096) {                       // query fp32 -> bf16
    int i = blk * 256 + tid;
    float4 v = ((const float4*)query)[i];
    ushort4 o;
    o.x = f2bf(v.x); o.y = f2bf(v.y); o.z = f2bf(v.z); o.w = f2bf(v.w);
    ((ushort4*)q_bf)[i] = o;
  } else if (blk < 8192) {                // W transpose+convert (32x32 tiles)
    const float* W; u16* Wt; int N, t;
    if (blk < 7168) { W = W_qkv; Wt = wt_qkv; N = NQKV; t = blk - 4096; }
    else            { W = W_out; Wt = wt_out; N = D_MODEL; t = blk - 7168; }
    int nb = N / 32;
    int c0 = (t % nb) * 32, r0 = (t / nb) * 32;
    int tx = tid & 31, ty = tid >> 5;
    for (int i = ty; i < 32; i += 8)
      tile[i][tx] = W[(size_t)(r0 + i) * N + c0 + tx];
    __syncthreads();
    for (int i = ty; i < 32; i += 8)
      Wt[(size_t)(c0 + i) * KDIM + r0 + tx] = f2bf(tile[tx][i]);
  } else if (blk < 8448) {                // rope table: tab[s*32+f] = (cos, sin)
    int i = (blk - 8192) * 256 + tid;
    int s = i >> 5, f = i & 31;
    float inv = __expf(-(float)f * 0.28782313662425572f);  // ln(1e4)/32
    float ang = (float)s * inv;
    rope_tab[i] = make_float2(cosf(ang), sinf(ang));
  } else {                                // out[row][col] = b_out[col] (split-K acc base)
    int i = (blk - 8448) * 256 + tid;     // 1,048,576 float4
    ((float4*)out)[i] = ((const float4*)b_out)[i & 255];
  }
}

// ---------------- QKV GEMM + bias + table-RoPE + coalesced scatter ----------------
// outputs PLAIN layouts: qb/kb[bh][s][hd], vtb[bh][hd][s]. q pre-scaled by kS.
__global__ __launch_bounds__(256) void qkv_gemm_kernel(
    const u16* __restrict__ A, const u16* __restrict__ Bt, const float* __restrict__ bias,
    const float2* __restrict__ rope_tab,
    u16* __restrict__ qb, u16* __restrict__ kb, u16* __restrict__ vtb) {
  __shared__ u16 smem[16384];            // As | Bs, reused by epilogue transpose
  u16* As = smem;
  u16* Bs = smem + 8192;
  const int tid = threadIdx.x;
  const int lane = tid & 63, wave = tid >> 6;
  const int wr = (wave >> 1) << 6, wc = (wave & 1) << 6;
  const int lrow = lane & 15, quad = lane >> 4;
  const int lk = quad * 8;
  const int rowA0 = blockIdx.y * 128, rowB0 = blockIdx.x * 128;

  f32x4 acc[4][4] = {};

  for (int k0 = 0; k0 < KDIM; k0 += 64) {
    __syncthreads();
#pragma unroll
    for (int it = 0; it < 4; ++it) {
      int flat = it * 256 + tid;
      int r = flat >> 3, c = (flat & 7) << 3;
      gload16(A + (size_t)(rowA0 + r) * KDIM + k0 + c, As + flat * 8);
      gload16(Bt + (size_t)(rowB0 + r) * KDIM + k0 + c, Bs + flat * 8);
    }
    __syncthreads();
#pragma unroll
    for (int kk = 0; kk < 64; kk += 32) {
      bf16x8 af[4], bfr[4];
#pragma unroll
      for (int mi = 0; mi < 4; ++mi)
        af[mi] = *(const bf16x8*)(As + (wr + mi * 16 + lrow) * 64 + kk + lk);
#pragma unroll
      for (int ni = 0; ni < 4; ++ni)
        bfr[ni] = *(const bf16x8*)(Bs + (wc + ni * 16 + lrow) * 64 + kk + lk);
#pragma unroll
      for (int mi = 0; mi < 4; ++mi)
#pragma unroll
        for (int ni = 0; ni < 4; ++ni)
          acc[mi][ni] = __builtin_amdgcn_mfma_f32_16x16x32_bf16(af[mi], bfr[ni], acc[mi][ni], 0, 0, 0);
    }
  }
  __syncthreads();   // all waves done with As/Bs before epilogue reuses smem

  const int col0 = rowB0 + wc;           // 64-aligned -> one head-slab per wave
  const int which = col0 >> 10;          // 0=q 1=k 2=v (wave-uniform)
  const int h = (col0 & 1023) >> 6;
  const int b = rowA0 >> 11;
  const int sbase = (rowA0 & 2047) + wr;

#pragma unroll
  for (int ni = 0; ni < 4; ++ni) {
    float bv = bias[col0 + ni * 16 + lrow];
#pragma unroll
    for (int mi = 0; mi < 4; ++mi)
#pragma unroll
      for (int r = 0; r < 4; ++r) acc[mi][ni][r] += bv;
  }

  if (which < 2) {
    // RoPE via table; q additionally pre-scaled by kS = log2(e)/sqrt(HD)
    const float qs = (which == 0) ? 0.18033688011112042f : 1.0f;
#pragma unroll
    for (int p = 0; p < 2; ++p) {
#pragma unroll
      for (int mi = 0; mi < 4; ++mi)
#pragma unroll
        for (int r = 0; r < 4; ++r) {
          int sg = sbase + mi * 16 + quad * 4 + r;
          float2 cs = rope_tab[sg * 32 + p * 16 + lrow];
          float x1 = acc[mi][p][r], x2 = acc[mi][p + 2][r];
          acc[mi][p][r]     = (x1 * cs.x - x2 * cs.y) * qs;
          acc[mi][p + 2][r] = (x2 * cs.x + x1 * cs.y) * qs;
        }
    }
    // in-wave LDS transpose (xor-swizzled cols), then coalesced 16B stores
    u16* myt = smem + wave * 4096;       // 64 x 64 bf16 slab
#pragma unroll
    for (int ni = 0; ni < 4; ++ni) {
      int hd = ni * 16 + lrow;
#pragma unroll
      for (int mi = 0; mi < 4; ++mi)
#pragma unroll
        for (int r = 0; r < 4; ++r) {
          int sl = mi * 16 + quad * 4 + r;
          int pos = ((((hd >> 3) ^ (sl & 7)) << 3)) | (hd & 7);
          myt[sl * 64 + pos] = f2bf(acc[mi][ni][r]);
        }
    }
    u16* dst = ((which == 0) ? qb : kb) + ((size_t)(b * NH + h) * SEQ + sbase) * HD;
    const int a = lane >> 3, pb = lane & 7;
#pragma unroll
    for (int it = 0; it < 8; ++it) {
      int sl = it * 8 + a;
      bf16x8 v = *(const bf16x8*)(myt + sl * 64 + (pb << 3));
      *(bf16x8*)(dst + sl * 64 + ((pb ^ a) << 3)) = v;   // undo swizzle -> plain
    }
  } else {
    // V^T: C-layout r-quad = 4 consecutive s at fixed hd -> packed 8B stores
    u16* dst = vtb + (size_t)(b * NH + h) * HD * SEQ;
#pragma unroll
    for (int ni = 0; ni < 4; ++ni) {
      int hd = ni * 16 + lrow;
#pragma unroll
      for (int mi = 0; mi < 4; ++mi) {
        ushort4 pk = packu4(acc[mi][ni][0], acc[mi][ni][1], acc[mi][ni][2], acc[mi][ni][3]);
        *(ushort4*)(dst + (size_t)hd * SEQ + sbase + mi * 16 + quad * 4) = pk;
      }
    }
  }
}

// ---------------- causal flash attention v4 ----------------
// Q pre-scaled by kS -> scores already in exp2 domain. 1024 blocks (heavy first),
// 64-key dbuf K/V tiles, Q fragments in registers, 32 KB LDS, 4 blocks/CU.
__global__ __launch_bounds__(256, 4) void flash_kernel(
    const u16* __restrict__ qb, const u16* __restrict__ kb,
    const u16* __restrict__ vtb, u16* __restrict__ attnb) {
  __shared__ u16 Ks[2][64 * 64];       // 16 KB
  __shared__ u16 Vts[2][64 * 64];      // 16 KB (hd x key)

  const int tid = threadIdx.x, lane = tid & 63, wave = tid >> 6;
  const int lrow = lane & 15, quad = lane >> 4;
  const int id = blockIdx.x;
  const int tile = 31 - (id >> 5);     // descending: heavy blocks dispatch first
  const int bh = id & 31;
  const int b = bh >> 4, h = bh & 15;

  const u16* qp = qb + (size_t)bh * SEQ * HD;
  const u16* kp = kb + (size_t)bh * SEQ * HD;
  const u16* vp = vtb + (size_t)bh * HD * SEQ;

  const int qg = tile * 64 + wave * 16 + lrow;   // this lane's q row
  bf16x8 bq0 = *(const bf16x8*)(qp + (size_t)qg * HD + quad * 8);
  bf16x8 bq1 = *(const bf16x8*)(qp + (size_t)qg * HD + 32 + quad * 8);

#pragma unroll
  for (int it = 0; it < 2; ++it) {     // stage K/V tile 0 into buf 0
    int f = it * 256 + tid;
    int r = f >> 3, c = f & 7;
    gload16(kp + (size_t)r * HD + (((c ^ (r & 7)) << 3)), Ks[0] + f * 8);
    gload16(vp + (size_t)r * SEQ + ((c ^ (r & 7)) << 3), Vts[0] + f * 8);
  }

  float m_i = -3.0e38f, l_i = 0.f;
  f32x4 oacc[4] = {};
  const int kmax = tile;
  const int sw = lrow & 7;

  for (int kt = 0; kt <= kmax; ++kt) {
    const int cur = kt & 1, nxt = cur ^ 1;
    __syncthreads();                   // drains cur staging; guards LDS reuse
    if (kt < kmax) {                   // async prefetch next tile over compute
#pragma unroll
      for (int it = 0; it < 2; ++it) {
        int f = it * 256 + tid;
        int r = f >> 3, c = f & 7;
        gload16(kp + (size_t)((kt + 1) * 64 + r) * HD + ((c ^ (r & 7)) << 3),
                Ks[nxt] + f * 8);
        gload16(vp + (size_t)r * SEQ + (kt + 1) * 64 + ((c ^ (r & 7)) << 3),
                Vts[nxt] + f * 8);
      }
    }

    // S^T = K·Q^T : lane holds S^T[key = ki*16+quad*4+r][q = qg] (exp2 units)
    f32x4 sc[4] = {};
#pragma unroll
    for (int hc = 0; hc < 2; ++hc) {
      bf16x8 bq = hc ? bq1 : bq0;
#pragma unroll
      for (int ki = 0; ki < 4; ++ki) {
        bf16x8 ak = *(const bf16x8*)(Ks[cur] + (ki * 16 + lrow) * 64 +
                                     (((hc * 4 + quad) ^ sw) << 3));
        sc[ki] = __builtin_amdgcn_mfma_f32_16x16x32_bf16(ak, bq, sc[ki], 0, 0, 0);
      }
    }

    if (kt == kmax) {                  // causal mask (diagonal tile only)
#pragma unroll
      for (int ki = 0; ki < 4; ++ki)
#pragma unroll
        for (int r = 0; r < 4; ++r)
          if (kt * 64 + ki * 16 + quad * 4 + r > qg) sc[ki][r] = -1e30f;
    }

    // online softmax (scores already log2-scaled): 16 in-lane + 2 shfls
    float mx = sc[0][0];
#pragma unroll
    for (int ki = 0; ki < 4; ++ki)
#pragma unroll
      for (int r = 0; r < 4; ++r) mx = fmaxf(mx, sc[ki][r]);
    mx = fmaxf(mx, __shfl_xor(mx, 16));
    mx = fmaxf(mx, __shfl_xor(mx, 32));
    float mnew = fmaxf(m_i, mx);
    float al = exp2f(m_i - mnew);
    float sum = 0.f;
#pragma unroll
    for (int ki = 0; ki < 4; ++ki)
#pragma unroll
      for (int r = 0; r < 4; ++r) {
        float p = exp2f(sc[ki][r] - mnew);
        sc[ki][r] = p;
        sum += p;
      }
    sum += __shfl_xor(sum, 16);
    sum += __shfl_xor(sum, 32);
    l_i = l_i * al + sum;
    m_i = mnew;
#pragma unroll
    for (int mi = 0; mi < 4; ++mi) oacc[mi] *= al;

    // P^T fragments via packed cvt: C-rows(=keys) ARE the K=16 B-frag layout
    bf16x4 pf[4];
#pragma unroll
    for (int ki = 0; ki < 4; ++ki)
      pf[ki] = pack4(sc[ki][0], sc[ki][1], sc[ki][2], sc[ki][3]);

    // O^T += V^T·P^T
#pragma unroll
    for (int mi = 0; mi < 4; ++mi) {
      int vrow = (mi * 16 + lrow) * 64;
#pragma unroll
      for (int ki = 0; ki < 4; ++ki) {
        bf16x4 av = *(const bf16x4*)(Vts[cur] + vrow +
                                     ((((ki * 2 + (quad >> 1)) ^ sw) << 3) | ((quad & 1) << 2)));
        oacc[mi] = mfma16(av, pf[ki], oacc[mi]);
      }
    }
  }

  // epilogue: lane owns q=qg entirely; packed cvt -> 8B stores
  float rl = 1.f / l_i;
  u16* op = attnb + ((size_t)(b * SEQ + qg)) * D_MODEL + h * HD;
#pragma unroll
  for (int mi = 0; mi < 4; ++mi) {
    ushort4 pk = packu4(oacc[mi][0] * rl, oacc[mi][1] * rl,
                        oacc[mi][2] * rl, oacc[mi][3] * rl);
    *(ushort4*)(op + mi * 16 + quad * 4) = pk;
  }
}

// -------- output projection: 128x128 tiles, split-K=2, atomic accumulate --------
// out pre-initialized with bias by prep_kernel.
__global__ __launch_bounds__(256) void out_gemm_kernel(
    const u16* __restrict__ A, const u16* __restrict__ Bt, float* __restrict__ out) {
  __shared__ u16 As[128 * 64];
  __shared__ u16 Bs[128 * 64];
  const int tid = threadIdx.x;
  const int lane = tid & 63, wave = tid >> 6;
  const int wr = (wave >> 1) << 6, wc = (wave & 1) << 6;
  const int lrow = lane & 15, quad = lane >> 4;
  const int lk = quad * 8;
  const int rowA0 = blockIdx.y * 128, rowB0 = blockIdx.x * 128;
  const int kbase = blockIdx.z * 512;

  f32x4 acc[4][4] = {};

  for (int k0 = kbase; k0 < kbase + 512; k0 += 64) {
    __syncthreads();
#pragma unroll
    for (int it = 0; it < 4; ++it) {
      int flat = it * 256 + tid;
      int r = flat >> 3, c = (flat & 7) << 3;
      gload16(A + (size_t)(rowA0 + r) * KDIM + k0 + c, As + flat * 8);
      gload16(Bt + (size_t)(rowB0 + r) * KDIM + k0 + c, Bs + flat * 8);
    }
    __syncthreads();
#pragma unroll
    for (int kk = 0; kk < 64; kk += 32) {
      bf16x8 af[4], bfr[4];
#pragma unroll
      for (int mi = 0; mi < 4; ++mi)
        af[mi] = *(const bf16x8*)(As + (wr + mi * 16 + lrow) * 64 + kk + lk);
#pragma unroll
      for (int ni = 0; ni < 4; ++ni)
        bfr[ni] = *(const bf16x8*)(Bs + (wc + ni * 16 + lrow) * 64 + kk + lk);
#pragma unroll
      for (int mi = 0; mi < 4; ++mi)
#pragma unroll
        for (int ni = 0; ni < 4; ++ni)
          acc[mi][ni] = __builtin_amdgcn_mfma_f32_16x16x32_bf16(af[mi], bfr[ni], acc[mi][ni], 0, 0, 0);
    }
  }

#pragma unroll
  for (int ni = 0; ni < 4; ++ni) {
    int col = rowB0 + wc + ni * 16 + lrow;
#pragma unroll
    for (int mi = 0; mi < 4; ++mi)
#pragma unroll
      for (int r = 0; r < 4; ++r) {
        int row = rowA0 + wr + mi * 16 + quad * 4 + r;
        unsafeAtomicAdd(&out[(size_t)row * D_MODEL + col], acc[mi][ni][r]);
      }
  }
}

extern "C" void kernel_launch(void* const* d_in, const int* in_sizes, int n_in,
                              void* d_out, int out_size, void* d_ws, size_t ws_size,
                              hipStream_t stream) {
  const float* query = (const float*)d_in[0];
  const float* W_qkv = (const float*)d_in[1];
  const float* b_qkv = (const float*)d_in[2];
  const float* W_out = (const float*)d_in[3];
  const float* b_out = (const float*)d_in[4];
  float* out = (float*)d_out;

  char* ws = (char*)d_ws;
  u16* q_bf    = (u16*)(ws);                 //  8 MB  query bf16 (4096x1024)
  u16* wt_qkv  = (u16*)(ws + 8388608);       //  6 MB  W_qkv^T bf16
  u16* wt_out  = (u16*)(ws + 14680064);      //  2 MB  W_out^T bf16
  u16* qbuf    = (u16*)(ws + 16777216);      //  8 MB  q (bh,s,hd) plain, pre-scaled kS
  u16* kbuf    = (u16*)(ws + 25165824);      //  8 MB  k (bh,s,hd) plain
  u16* vtbuf   = (u16*)(ws + 33554432);      //  8 MB  v^T (bh,hd,s) plain
  u16* attnb   = (u16*)(ws + 41943040);      //  8 MB  attn (B,S,D) bf16
  float2* rope = (float2*)(ws + 50331648);   // 512 KB rope table (s,freq)

  prep_kernel<<<dim3(12544), dim3(256), 0, stream>>>(query, q_bf, W_qkv, wt_qkv,
                                                     W_out, wt_out, rope, b_out, out);
  qkv_gemm_kernel<<<dim3(NQKV / 128, ROWS / 128), dim3(256), 0, stream>>>(
      q_bf, wt_qkv, b_qkv, rope, qbuf, kbuf, vtbuf);
  flash_kernel<<<dim3(1024), dim3(256), 0, stream>>>(qbuf, kbuf, vtbuf, attnb);
  out_gemm_kernel<<<dim3(D_MODEL / 128, ROWS / 128, 2), dim3(256), 0, stream>>>(
      attnb, wt_out, out);
}

// Round 5
// 195.252 us; speedup vs baseline: 1.1649x; 1.1649x over previous
//
#include <hip/hip_runtime.h>
#include <hip/hip_bf16.h>
#include <stdint.h>

#define D_MODEL 1024
#define NH 16
#define HD 64
#define SEQ 2048
#define BATCH 2
#define ROWS (BATCH * SEQ)   // 4096
#define KDIM 1024
#define NQKV 3072

typedef unsigned short u16;
typedef short bf16x8 __attribute__((ext_vector_type(8)));   // 8 bf16 in 4 VGPRs
typedef short bf16x4 __attribute__((ext_vector_type(4)));   // 4 bf16 in 2 VGPRs
typedef float f32x4 __attribute__((ext_vector_type(4)));

__device__ __forceinline__ u16 f2bf(float f) {
  union { float f; unsigned u; } x; x.f = f;
  unsigned r = x.u + 0x7fff + ((x.u >> 16) & 1);   // RNE
  return (u16)(r >> 16);
}

// packed RNE f32x2 -> bf16x2 (v_cvt_pk_bf16_f32 on gfx950)
__device__ __forceinline__ bf16x4 pack4(float a, float b, float c, float d) {
  union { __hip_bfloat162 h2[2]; bf16x4 v; } u;
  u.h2[0] = __float22bfloat162_rn(make_float2(a, b));
  u.h2[1] = __float22bfloat162_rn(make_float2(c, d));
  return u.v;
}
__device__ __forceinline__ ushort4 packu4(float a, float b, float c, float d) {
  union { __hip_bfloat162 h2[2]; ushort4 v; } u;
  u.h2[0] = __float22bfloat162_rn(make_float2(a, b));
  u.h2[1] = __float22bfloat162_rn(make_float2(c, d));
  return u.v;
}

#ifndef HAVE_MFMA16_1K
#if defined(__has_builtin)
#if __has_builtin(__builtin_amdgcn_mfma_f32_16x16x16bf16_1k)
#define HAVE_MFMA16_1K 1
#endif
#endif
#endif
__device__ __forceinline__ f32x4 mfma16(bf16x4 a, bf16x4 b, f32x4 c) {
#ifdef HAVE_MFMA16_1K
  return __builtin_amdgcn_mfma_f32_16x16x16bf16_1k(a, b, c, 0, 0, 0);
#else
  bf16x8 a8 = {a[0], a[1], a[2], a[3], 0, 0, 0, 0};
  bf16x8 b8 = {b[0], b[1], b[2], b[3], 0, 0, 0, 0};
  return __builtin_amdgcn_mfma_f32_16x16x32_bf16(a8, b8, c, 0, 0, 0);
#endif
}

// async global->LDS, 16B/lane. LDS dst is wave-uniform base + lane*16;
// global SOURCE address is per-lane arbitrary (16B contiguous) -> swizzle there.
__device__ __forceinline__ void gload16(const u16* g, u16* l) {
  __builtin_amdgcn_global_load_lds(
      (const __attribute__((address_space(1))) unsigned int*)g,
      (__attribute__((address_space(3))) unsigned int*)l, 16, 0, 0);
}

// ---- fused prep: query cvt, weight transposes, rope table ----
__global__ void prep_kernel(const float* __restrict__ query, u16* __restrict__ q_bf,
                            const float* __restrict__ W_qkv, u16* __restrict__ wt_qkv,
                            const float* __restrict__ W_out, u16* __restrict__ wt_out,
                            float2* __restrict__ rope_tab) {
  __shared__ float tile[32][33];
  const int blk = blockIdx.x, tid = threadIdx.x;
  if (blk < 4096) {                       // query fp32 -> bf16
    int i = blk * 256 + tid;
    float4 v = ((const float4*)query)[i];
    ushort4 o;
    o.x = f2bf(v.x); o.y = f2bf(v.y); o.z = f2bf(v.z); o.w = f2bf(v.w);
    ((ushort4*)q_bf)[i] = o;
  } else if (blk < 8192) {                // W transpose+convert (32x32 tiles)
    const float* W; u16* Wt; int N, t;
    if (blk < 7168) { W = W_qkv; Wt = wt_qkv; N = NQKV; t = blk - 4096; }
    else            { W = W_out; Wt = wt_out; N = D_MODEL; t = blk - 7168; }
    int nb = N / 32;
    int c0 = (t % nb) * 32, r0 = (t / nb) * 32;
    int tx = tid & 31, ty = tid >> 5;
    for (int i = ty; i < 32; i += 8)
      tile[i][tx] = W[(size_t)(r0 + i) * N + c0 + tx];
    __syncthreads();
    for (int i = ty; i < 32; i += 8)
      Wt[(size_t)(c0 + i) * KDIM + r0 + tx] = f2bf(tile[tx][i]);
  } else {                                // rope table: tab[s*32+f] = (cos, sin)
    int i = (blk - 8192) * 256 + tid;
    int s = i >> 5, f = i & 31;
    float inv = __expf(-(float)f * 0.28782313662425572f);  // ln(1e4)/32
    float ang = (float)s * inv;
    rope_tab[i] = make_float2(cosf(ang), sinf(ang));
  }
}

// ---------------- QKV GEMM + bias + table-RoPE + coalesced scatter ----------------
// LDS XOR-swizzled (chunk c stored at c^(r&7) via gload16 source addr) to kill
// the 16-way row-stride-128B bank conflicts on fragment reads.
// outputs PLAIN layouts: qb/kb[bh][s][hd], vtb[bh][hd][s]. q pre-scaled by kS.
__global__ __launch_bounds__(256) void qkv_gemm_kernel(
    const u16* __restrict__ A, const u16* __restrict__ Bt, const float* __restrict__ bias,
    const float2* __restrict__ rope_tab,
    u16* __restrict__ qb, u16* __restrict__ kb, u16* __restrict__ vtb) {
  __shared__ u16 smem[16384];            // As | Bs, reused by epilogue transpose
  u16* As = smem;
  u16* Bs = smem + 8192;
  const int tid = threadIdx.x;
  const int lane = tid & 63, wave = tid >> 6;
  const int wr = (wave >> 1) << 6, wc = (wave & 1) << 6;
  const int lrow = lane & 15, quad = lane >> 4;
  const int sw = lrow & 7;
  const int rowA0 = blockIdx.y * 128, rowB0 = blockIdx.x * 128;

  f32x4 acc[4][4] = {};

  for (int k0 = 0; k0 < KDIM; k0 += 64) {
    __syncthreads();
#pragma unroll
    for (int it = 0; it < 4; ++it) {
      int flat = it * 256 + tid;
      int r = flat >> 3, cs = ((flat & 7) ^ (r & 7)) << 3;   // source swizzle
      gload16(A + (size_t)(rowA0 + r) * KDIM + k0 + cs, As + flat * 8);
      gload16(Bt + (size_t)(rowB0 + r) * KDIM + k0 + cs, Bs + flat * 8);
    }
    __syncthreads();
#pragma unroll
    for (int kk = 0; kk < 64; kk += 32) {
      const int ch = ((kk >> 3) + quad) ^ sw;    // swizzled chunk, uniform per lane
      bf16x8 af[4], bfr[4];
#pragma unroll
      for (int mi = 0; mi < 4; ++mi)
        af[mi] = *(const bf16x8*)(As + (wr + mi * 16 + lrow) * 64 + (ch << 3));
#pragma unroll
      for (int ni = 0; ni < 4; ++ni)
        bfr[ni] = *(const bf16x8*)(Bs + (wc + ni * 16 + lrow) * 64 + (ch << 3));
#pragma unroll
      for (int mi = 0; mi < 4; ++mi)
#pragma unroll
        for (int ni = 0; ni < 4; ++ni)
          acc[mi][ni] = __builtin_amdgcn_mfma_f32_16x16x32_bf16(af[mi], bfr[ni], acc[mi][ni], 0, 0, 0);
    }
  }
  __syncthreads();   // all waves done with As/Bs before epilogue reuses smem

  const int col0 = rowB0 + wc;           // 64-aligned -> one head-slab per wave
  const int which = col0 >> 10;          // 0=q 1=k 2=v (wave-uniform)
  const int h = (col0 & 1023) >> 6;
  const int b = rowA0 >> 11;
  const int sbase = (rowA0 & 2047) + wr;

#pragma unroll
  for (int ni = 0; ni < 4; ++ni) {
    float bv = bias[col0 + ni * 16 + lrow];
#pragma unroll
    for (int mi = 0; mi < 4; ++mi)
#pragma unroll
      for (int r = 0; r < 4; ++r) acc[mi][ni][r] += bv;
  }

  if (which < 2) {
    // RoPE via table; q additionally pre-scaled by kS = log2(e)/sqrt(HD)
    const float qs = (which == 0) ? 0.18033688011112042f : 1.0f;
#pragma unroll
    for (int p = 0; p < 2; ++p) {
#pragma unroll
      for (int mi = 0; mi < 4; ++mi)
#pragma unroll
        for (int r = 0; r < 4; ++r) {
          int sg = sbase + mi * 16 + quad * 4 + r;
          float2 cs = rope_tab[sg * 32 + p * 16 + lrow];
          float x1 = acc[mi][p][r], x2 = acc[mi][p + 2][r];
          acc[mi][p][r]     = (x1 * cs.x - x2 * cs.y) * qs;
          acc[mi][p + 2][r] = (x2 * cs.x + x1 * cs.y) * qs;
        }
    }
    // in-wave LDS transpose (xor-swizzled cols), then coalesced 16B stores
    u16* myt = smem + wave * 4096;       // 64 x 64 bf16 slab
#pragma unroll
    for (int ni = 0; ni < 4; ++ni) {
      int hd = ni * 16 + lrow;
#pragma unroll
      for (int mi = 0; mi < 4; ++mi)
#pragma unroll
        for (int r = 0; r < 4; ++r) {
          int sl = mi * 16 + quad * 4 + r;
          int pos = ((((hd >> 3) ^ (sl & 7)) << 3)) | (hd & 7);
          myt[sl * 64 + pos] = f2bf(acc[mi][ni][r]);
        }
    }
    u16* dst = ((which == 0) ? qb : kb) + ((size_t)(b * NH + h) * SEQ + sbase) * HD;
    const int a = lane >> 3, pb = lane & 7;
#pragma unroll
    for (int it = 0; it < 8; ++it) {
      int sl = it * 8 + a;
      bf16x8 v = *(const bf16x8*)(myt + sl * 64 + (pb << 3));
      *(bf16x8*)(dst + sl * 64 + ((pb ^ a) << 3)) = v;   // undo swizzle -> plain
    }
  } else {
    // V^T: C-layout r-quad = 4 consecutive s at fixed hd -> packed 8B stores
    u16* dst = vtb + (size_t)(b * NH + h) * HD * SEQ;
#pragma unroll
    for (int ni = 0; ni < 4; ++ni) {
      int hd = ni * 16 + lrow;
#pragma unroll
      for (int mi = 0; mi < 4; ++mi) {
        ushort4 pk = packu4(acc[mi][ni][0], acc[mi][ni][1], acc[mi][ni][2], acc[mi][ni][3]);
        *(ushort4*)(dst + (size_t)hd * SEQ + sbase + mi * 16 + quad * 4) = pk;
      }
    }
  }
}

// ---------------- causal flash attention v4 ----------------
// Q pre-scaled by kS -> scores already in exp2 domain. 1024 blocks (heavy first),
// 64-key dbuf K/V tiles, Q fragments in registers, 32 KB LDS, 4 blocks/CU.
__global__ __launch_bounds__(256, 4) void flash_kernel(
    const u16* __restrict__ qb, const u16* __restrict__ kb,
    const u16* __restrict__ vtb, u16* __restrict__ attnb) {
  __shared__ u16 Ks[2][64 * 64];       // 16 KB
  __shared__ u16 Vts[2][64 * 64];      // 16 KB (hd x key)

  const int tid = threadIdx.x, lane = tid & 63, wave = tid >> 6;
  const int lrow = lane & 15, quad = lane >> 4;
  const int id = blockIdx.x;
  const int tile = 31 - (id >> 5);     // descending: heavy blocks dispatch first
  const int bh = id & 31;
  const int b = bh >> 4, h = bh & 15;

  const u16* qp = qb + (size_t)bh * SEQ * HD;
  const u16* kp = kb + (size_t)bh * SEQ * HD;
  const u16* vp = vtb + (size_t)bh * HD * SEQ;

  const int qg = tile * 64 + wave * 16 + lrow;   // this lane's q row
  bf16x8 bq0 = *(const bf16x8*)(qp + (size_t)qg * HD + quad * 8);
  bf16x8 bq1 = *(const bf16x8*)(qp + (size_t)qg * HD + 32 + quad * 8);

#pragma unroll
  for (int it = 0; it < 2; ++it) {     // stage K/V tile 0 into buf 0
    int f = it * 256 + tid;
    int r = f >> 3, c = f & 7;
    gload16(kp + (size_t)r * HD + (((c ^ (r & 7)) << 3)), Ks[0] + f * 8);
    gload16(vp + (size_t)r * SEQ + ((c ^ (r & 7)) << 3), Vts[0] + f * 8);
  }

  float m_i = -3.0e38f, l_i = 0.f;
  f32x4 oacc[4] = {};
  const int kmax = tile;
  const int sw = lrow & 7;

  for (int kt = 0; kt <= kmax; ++kt) {
    const int cur = kt & 1, nxt = cur ^ 1;
    __syncthreads();                   // drains cur staging; guards LDS reuse
    if (kt < kmax) {                   // async prefetch next tile over compute
#pragma unroll
      for (int it = 0; it < 2; ++it) {
        int f = it * 256 + tid;
        int r = f >> 3, c = f & 7;
        gload16(kp + (size_t)((kt + 1) * 64 + r) * HD + ((c ^ (r & 7)) << 3),
                Ks[nxt] + f * 8);
        gload16(vp + (size_t)r * SEQ + (kt + 1) * 64 + ((c ^ (r & 7)) << 3),
                Vts[nxt] + f * 8);
      }
    }

    // S^T = K·Q^T : lane holds S^T[key = ki*16+quad*4+r][q = qg] (exp2 units)
    f32x4 sc[4] = {};
#pragma unroll
    for (int hc = 0; hc < 2; ++hc) {
      bf16x8 bq = hc ? bq1 : bq0;
#pragma unroll
      for (int ki = 0; ki < 4; ++ki) {
        bf16x8 ak = *(const bf16x8*)(Ks[cur] + (ki * 16 + lrow) * 64 +
                                     (((hc * 4 + quad) ^ sw) << 3));
        sc[ki] = __builtin_amdgcn_mfma_f32_16x16x32_bf16(ak, bq, sc[ki], 0, 0, 0);
      }
    }

    if (kt == kmax) {                  // causal mask (diagonal tile only)
#pragma unroll
      for (int ki = 0; ki < 4; ++ki)
#pragma unroll
        for (int r = 0; r < 4; ++r)
          if (kt * 64 + ki * 16 + quad * 4 + r > qg) sc[ki][r] = -1e30f;
    }

    // online softmax (scores already log2-scaled): 16 in-lane + 2 shfls
    float mx = sc[0][0];
#pragma unroll
    for (int ki = 0; ki < 4; ++ki)
#pragma unroll
      for (int r = 0; r < 4; ++r) mx = fmaxf(mx, sc[ki][r]);
    mx = fmaxf(mx, __shfl_xor(mx, 16));
    mx = fmaxf(mx, __shfl_xor(mx, 32));
    float mnew = fmaxf(m_i, mx);
    float al = exp2f(m_i - mnew);
    float sum = 0.f;
#pragma unroll
    for (int ki = 0; ki < 4; ++ki)
#pragma unroll
      for (int r = 0; r < 4; ++r) {
        float p = exp2f(sc[ki][r] - mnew);
        sc[ki][r] = p;
        sum += p;
      }
    sum += __shfl_xor(sum, 16);
    sum += __shfl_xor(sum, 32);
    l_i = l_i * al + sum;
    m_i = mnew;
#pragma unroll
    for (int mi = 0; mi < 4; ++mi) oacc[mi] *= al;

    // P^T fragments via packed cvt: C-rows(=keys) ARE the K=16 B-frag layout
    bf16x4 pf[4];
#pragma unroll
    for (int ki = 0; ki < 4; ++ki)
      pf[ki] = pack4(sc[ki][0], sc[ki][1], sc[ki][2], sc[ki][3]);

    // O^T += V^T·P^T
#pragma unroll
    for (int mi = 0; mi < 4; ++mi) {
      int vrow = (mi * 16 + lrow) * 64;
#pragma unroll
      for (int ki = 0; ki < 4; ++ki) {
        bf16x4 av = *(const bf16x4*)(Vts[cur] + vrow +
                                     ((((ki * 2 + (quad >> 1)) ^ sw) << 3) | ((quad & 1) << 2)));
        oacc[mi] = mfma16(av, pf[ki], oacc[mi]);
      }
    }
  }

  // epilogue: lane owns q=qg entirely; packed cvt -> 8B stores
  float rl = 1.f / l_i;
  u16* op = attnb + ((size_t)(b * SEQ + qg)) * D_MODEL + h * HD;
#pragma unroll
  for (int mi = 0; mi < 4; ++mi) {
    ushort4 pk = packu4(oacc[mi][0] * rl, oacc[mi][1] * rl,
                        oacc[mi][2] * rl, oacc[mi][3] * rl);
    *(ushort4*)(op + mi * 16 + quad * 4) = pk;
  }
}

// -------- output projection: 128x64 tiles, 512 blocks (2/CU), swizzled LDS ------
__global__ __launch_bounds__(256) void out_gemm_kernel(
    const u16* __restrict__ A, const u16* __restrict__ Bt, const float* __restrict__ bias,
    float* __restrict__ out) {
  __shared__ u16 As[128 * 64];
  __shared__ u16 Bs[64 * 64];
  const int tid = threadIdx.x;
  const int lane = tid & 63, wave = tid >> 6;
  const int lrow = lane & 15, quad = lane >> 4;
  const int sw = lrow & 7;
  const int wr = wave * 32;
  const int rowA0 = blockIdx.y * 128, colB0 = blockIdx.x * 64;

  f32x4 acc[2][4] = {};

  for (int k0 = 0; k0 < KDIM; k0 += 64) {
    __syncthreads();
#pragma unroll
    for (int it = 0; it < 4; ++it) {
      int f = it * 256 + tid;
      int r = f >> 3, cs = ((f & 7) ^ (r & 7)) << 3;
      gload16(A + (size_t)(rowA0 + r) * KDIM + k0 + cs, As + f * 8);
    }
#pragma unroll
    for (int it = 0; it < 2; ++it) {
      int f = it * 256 + tid;
      int r = f >> 3, cs = ((f & 7) ^ (r & 7)) << 3;
      gload16(Bt + (size_t)(colB0 + r) * KDIM + k0 + cs, Bs + f * 8);
    }
    __syncthreads();
#pragma unroll
    for (int kk = 0; kk < 64; kk += 32) {
      const int ch = ((kk >> 3) + quad) ^ sw;
      bf16x8 af[2], bfr[4];
#pragma unroll
      for (int mi = 0; mi < 2; ++mi)
        af[mi] = *(const bf16x8*)(As + (wr + mi * 16 + lrow) * 64 + (ch << 3));
#pragma unroll
      for (int ni = 0; ni < 4; ++ni)
        bfr[ni] = *(const bf16x8*)(Bs + (ni * 16 + lrow) * 64 + (ch << 3));
#pragma unroll
      for (int mi = 0; mi < 2; ++mi)
#pragma unroll
        for (int ni = 0; ni < 4; ++ni)
          acc[mi][ni] = __builtin_amdgcn_mfma_f32_16x16x32_bf16(af[mi], bfr[ni], acc[mi][ni], 0, 0, 0);
    }
  }

#pragma unroll
  for (int ni = 0; ni < 4; ++ni) {
    int col = colB0 + ni * 16 + lrow;
    float bv = bias[col];
#pragma unroll
    for (int mi = 0; mi < 2; ++mi)
#pragma unroll
      for (int r = 0; r < 4; ++r) {
        int row = rowA0 + wr + mi * 16 + quad * 4 + r;
        out[(size_t)row * D_MODEL + col] = acc[mi][ni][r] + bv;
      }
  }
}

extern "C" void kernel_launch(void* const* d_in, const int* in_sizes, int n_in,
                              void* d_out, int out_size, void* d_ws, size_t ws_size,
                              hipStream_t stream) {
  const float* query = (const float*)d_in[0];
  const float* W_qkv = (const float*)d_in[1];
  const float* b_qkv = (const float*)d_in[2];
  const float* W_out = (const float*)d_in[3];
  const float* b_out = (const float*)d_in[4];
  float* out = (float*)d_out;

  char* ws = (char*)d_ws;
  u16* q_bf    = (u16*)(ws);                 //  8 MB  query bf16 (4096x1024)
  u16* wt_qkv  = (u16*)(ws + 8388608);       //  6 MB  W_qkv^T bf16
  u16* wt_out  = (u16*)(ws + 14680064);      //  2 MB  W_out^T bf16
  u16* qbuf    = (u16*)(ws + 16777216);      //  8 MB  q (bh,s,hd) plain, pre-scaled kS
  u16* kbuf    = (u16*)(ws + 25165824);      //  8 MB  k (bh,s,hd) plain
  u16* vtbuf   = (u16*)(ws + 33554432);      //  8 MB  v^T (bh,hd,s) plain
  u16* attnb   = (u16*)(ws + 41943040);      //  8 MB  attn (B,S,D) bf16
  float2* rope = (float2*)(ws + 50331648);   // 512 KB rope table (s,freq)

  prep_kernel<<<dim3(8448), dim3(256), 0, stream>>>(query, q_bf, W_qkv, wt_qkv,
                                                    W_out, wt_out, rope);
  qkv_gemm_kernel<<<dim3(NQKV / 128, ROWS / 128), dim3(256), 0, stream>>>(
      q_bf, wt_qkv, b_qkv, rope, qbuf, kbuf, vtbuf);
  flash_kernel<<<dim3(1024), dim3(256), 0, stream>>>(qbuf, kbuf, vtbuf, attnb);
  out_gemm_kernel<<<dim3(D_MODEL / 64, ROWS / 128), dim3(256), 0, stream>>>(
      attnb, wt_out, b_out, out);
}